// Round 5
// baseline (81.246 us; speedup 1.0000x reference)
//
#include <hip/hip_runtime.h>
#include <hip/hip_bf16.h>
#include <math.h>

#define WINDOW 50

typedef __attribute__((ext_vector_type(8))) short short8;
typedef __attribute__((ext_vector_type(4))) float f32x4;
typedef unsigned int uint;

union U8 { uint4 u; short8 s; };
__device__ inline short8 as_s8(uint4 u) { U8 t; t.u = u; return t.s; }

__device__ inline uint pk2(float a, float b) {
    uint r;
    asm("v_cvt_pk_bf16_f32 %0, %1, %2" : "=v"(r) : "v"(a), "v"(b));
    return r;
}
__device__ inline float lo_f32(uint u) { return __uint_as_float(u << 16); }
__device__ inline float hi_f32(uint u) { return __uint_as_float(u & 0xffff0000u); }

// Persistent-block transposed-GEMM design (window = MFMA column everywhere).
// Exact splits as r4: stats hi/lo K-packed, b1 via K16 x 1.0, w2 hi/lo frag
// sets, h1 hi/lo. 2 tiles/block, frag build amortized; stat broadcast via
// shfl (no s_stat LDS); L2 split into two 3-deep MFMA accumulators.
__global__ __launch_bounds__(256, 5) void nsg_kernel(
    const float* __restrict__ x,
    const float* __restrict__ w1, const float* __restrict__ b1,
    const float* __restrict__ w2, const float* __restrict__ b2,
    const float* __restrict__ w3, const float* __restrict__ b3,
    float* __restrict__ out, int N, int M, int nunits)
{
    __shared__ float s_x[312];            // 306 used
    __shared__ uint4 s_bufq[1088];        // chunks overlay / per-wave h1 (272 each)
    __shared__ uint4 s_a2l[4][64];        // w2-lo fragments

    const int tid = threadIdx.x;
    const int wv  = tid >> 6;
    const int wl  = tid & 63;
    const int l15 = wl & 15;
    const int g   = wl >> 4;

    // ---- one-time per-block: constant fragments ----
    // A1: w1^T; g0 = w1hi pairs (x2), g1 = w1lo pairs (x2), g2 = (b1hi,b1lo) vs 1.0
    short8 A1[4];
    #pragma unroll
    for (int nt = 0; nt < 4; ++nt) {
        int n = nt * 16 + l15;
        float a = w1[n], b = w1[64 + n], c = w1[128 + n], d = w1[192 + n];
        uint hab = pk2(a, b), hcd = pk2(c, d);
        uint lab = pk2(a - lo_f32(hab), b - hi_f32(hab));
        uint lcd = pk2(c - lo_f32(hcd), d - hi_f32(hcd));
        float bb = b1[n];
        uint bh  = pk2(bb, 0.0f);
        uint bpk = pk2(bb, bb - lo_f32(bh));
        uint4 u;
        u.x = (g == 0) ? hab : (g == 1) ? lab : (g == 2) ? bpk : 0u;
        u.y = (g == 0) ? hcd : (g == 1) ? lcd : 0u;
        u.z = (g == 0) ? hab : (g == 1) ? lab : 0u;
        u.w = (g == 0) ? hcd : (g == 1) ? lcd : 0u;
        A1[nt] = as_s8(u);
    }
    // A2: w2^T hi in VGPR, lo staged to LDS by wave 0
    uint4 A2h[2][2];
    #pragma unroll
    for (int mt = 0; mt < 2; ++mt) {
        int c = mt * 16 + l15;
        #pragma unroll
        for (int ks = 0; ks < 2; ++ks) {
            uint hu[4], lu[4];
            #pragma unroll
            for (int p = 0; p < 4; ++p) {
                int n = ks * 32 + g * 8 + 2 * p;
                float a = w2[n * 32 + c], b = w2[(n + 1) * 32 + c];
                uint h = pk2(a, b);
                hu[p] = h;
                lu[p] = pk2(a - lo_f32(h), b - hi_f32(h));
            }
            A2h[mt][ks] = make_uint4(hu[0], hu[1], hu[2], hu[3]);
            if (wv == 0) s_a2l[mt * 2 + ks][wl] = make_uint4(lu[0], lu[1], lu[2], lu[3]);
        }
    }
    f32x4 b2r[2];
    #pragma unroll
    for (int mt = 0; mt < 2; ++mt)
        b2r[mt] = *(const f32x4*)(b2 + 16 * mt + 4 * g);
    float2 w3r[8];
    #pragma unroll
    for (int mt = 0; mt < 2; ++mt)
        #pragma unroll
        for (int j = 0; j < 4; ++j)
            w3r[mt * 4 + j] = *(const float2*)(w3 + (16 * mt + 4 * g + j) * 2);
    const float b3g = b3[0], b3b = b3[1];
    const uint  K2  = (g == 2) ? 0x3F803F80u : 0u;   // (1.0,1.0) bf16
    const bool  gHi = (g >= 2);

    uint* h1b = (uint*)(s_bufq + 272 * wv);
    f32x4* s_chunk = (f32x4*)s_bufq;

    __syncthreads();   // s_a2l ready

    // ---- persistent loop: 2 units (tiles of 256 windows) per block ----
    #pragma unroll 1
    for (int k = 0; k < 2; ++k) {
        int u = 2 * (int)blockIdx.x + k;
        if (u >= nunits) break;
        const int row = u >> 7;
        const int m0  = (u & 127) * 256;
        const float* xr = x + (size_t)row * N;

        // stage x (+halo), clamped
        for (int i = tid; i < 306; i += 256) {
            int gg = m0 + i;
            s_x[i] = (gg < N) ? xr[gg] : 0.0f;
        }
        __syncthreads();   // s_x ready; prev-unit h1 region free

        // chunk moment-sums (10-wide)
        f32x4 myC;
        {
            float S1 = 0.f, S2 = 0.f, S3 = 0.f, S4 = 0.f;
            #pragma unroll
            for (int i = 0; i < 10; ++i) {
                float v = s_x[tid + i], v2 = v * v;
                S1 += v; S2 += v2; S3 = fmaf(v2, v, S3); S4 = fmaf(v2, v2, S4);
            }
            myC = f32x4{S1, S2, S3, S4};
            s_chunk[tid] = myC;
        }
        if (tid < 40) {
            int t = tid + 256;
            float S1 = 0.f, S2 = 0.f, S3 = 0.f, S4 = 0.f;
            #pragma unroll
            for (int i = 0; i < 10; ++i) {
                float v = s_x[t + i], v2 = v * v;
                S1 += v; S2 += v2; S3 = fmaf(v2, v, S3); S4 = fmaf(v2, v2, S4);
            }
            s_chunk[t] = f32x4{S1, S2, S3, S4};
        }
        __syncthreads();   // chunks ready

        // window moments (5 chunks) + split-pack
        f32x4 ca = s_chunk[tid + 10], cb = s_chunk[tid + 20];
        f32x4 cc = s_chunk[tid + 30], cd = s_chunk[tid + 40];
        float S1 = myC[0] + ca[0] + cb[0] + cc[0] + cd[0];
        float S2 = myC[1] + ca[1] + cb[1] + cc[1] + cd[1];
        float S3 = myC[2] + ca[2] + cb[2] + cc[2] + cd[2];
        float S4 = myC[3] + ca[3] + cb[3] + cc[3] + cd[3];
        const float invW = 1.0f / (float)WINDOW;
        float mean = S1 * invW;
        float mu2  = mean * mean;
        float c2m = S2 - (float)WINDOW * mu2;
        float c3m = S3 - 3.0f * mean * S2 + 2.0f * (float)WINDOW * mu2 * mean;
        float c4m = S4 - 4.0f * mean * S3 + 6.0f * mu2 * S2
                      - 3.0f * (float)WINDOW * mu2 * mu2;
        float var    = c2m * (1.0f / (float)(WINDOW - 1));
        float sd     = sqrtf(var) + 1e-6f;
        float inv_sd = 1.0f / sd;
        float inv_sd2 = inv_sd * inv_sd;
        float skew = c3m * invW * inv_sd2 * inv_sd;
        float kurt = c4m * invW * inv_sd2 * inv_sd2;
        float nrm  = (s_x[tid + 25] - mean) * inv_sd;

        uint4 stp;
        {
            uint h01 = pk2(mean, sd), h23 = pk2(skew, kurt);
            stp.x = h01;
            stp.y = h23;
            stp.z = pk2(mean - lo_f32(h01), sd - hi_f32(h01));
            stp.w = pk2(skew - lo_f32(h23), kurt - hi_f32(h23));
        }
        __syncthreads();   // chunk reads done -> h1 region reusable

        // quarter loop: stats shfl -> L1 -> h1 split -> L2 -> L3 reduce
        float ga = 0.f, be = 0.f;
        #pragma unroll
        for (int q = 0; q < 4; ++q) {
            const int src = q * 16 + l15;
            uint4 st;
            st.x = __shfl(stp.x, src, 64);
            st.y = __shfl(stp.y, src, 64);
            st.z = __shfl(stp.z, src, 64);
            st.w = __shfl(stp.w, src, 64);
            uint4 bq;
            bq.x = gHi ? K2 : st.x;
            bq.y = gHi ? 0u : st.y;
            bq.z = gHi ? 0u : st.z;
            bq.w = gHi ? 0u : st.w;
            short8 B1 = as_s8(bq);

            #pragma unroll
            for (int nt = 0; nt < 4; ++nt) {
                f32x4 c1 = f32x4{0.f, 0.f, 0.f, 0.f};
                c1 = __builtin_amdgcn_mfma_f32_16x16x32_bf16(A1[nt], B1, c1, 0, 0, 0);
                float r0 = fmaxf(c1[0], 0.f), r1 = fmaxf(c1[1], 0.f);
                float r2 = fmaxf(c1[2], 0.f), r3 = fmaxf(c1[3], 0.f);
                uint h01 = pk2(r0, r1), h23 = pk2(r2, r3);
                uint q01 = pk2(r0 - lo_f32(h01), r1 - hi_f32(h01));
                uint q23 = pk2(r2 - lo_f32(h23), r3 - hi_f32(h23));
                int d = l15 * 68 + 8 * nt + 2 * g;
                *(uint2*)&h1b[d]      = make_uint2(h01, h23);
                *(uint2*)&h1b[d + 32] = make_uint2(q01, q23);
            }
            __builtin_amdgcn_wave_barrier();

            short8 Bh0 = as_s8(*(uint4*)&h1b[l15 * 68 +  0 + 4 * g]);
            short8 Bh1 = as_s8(*(uint4*)&h1b[l15 * 68 + 16 + 4 * g]);
            short8 Bl0 = as_s8(*(uint4*)&h1b[l15 * 68 + 32 + 4 * g]);
            short8 Bl1 = as_s8(*(uint4*)&h1b[l15 * 68 + 48 + 4 * g]);

            float pg = 0.f, pb = 0.f;
            #pragma unroll
            for (int mt = 0; mt < 2; ++mt) {
                short8 a2l0 = as_s8(s_a2l[mt * 2 + 0][wl]);
                short8 a2l1 = as_s8(s_a2l[mt * 2 + 1][wl]);
                // two 3-deep chains instead of one 6-deep
                f32x4 c2a = b2r[mt];
                c2a = __builtin_amdgcn_mfma_f32_16x16x32_bf16(as_s8(A2h[mt][0]), Bh0, c2a, 0, 0, 0);
                c2a = __builtin_amdgcn_mfma_f32_16x16x32_bf16(as_s8(A2h[mt][1]), Bh1, c2a, 0, 0, 0);
                c2a = __builtin_amdgcn_mfma_f32_16x16x32_bf16(a2l0, Bh0, c2a, 0, 0, 0);
                f32x4 c2b = f32x4{0.f, 0.f, 0.f, 0.f};
                c2b = __builtin_amdgcn_mfma_f32_16x16x32_bf16(as_s8(A2h[mt][0]), Bl0, c2b, 0, 0, 0);
                c2b = __builtin_amdgcn_mfma_f32_16x16x32_bf16(as_s8(A2h[mt][1]), Bl1, c2b, 0, 0, 0);
                c2b = __builtin_amdgcn_mfma_f32_16x16x32_bf16(a2l1, Bh1, c2b, 0, 0, 0);
                #pragma unroll
                for (int j = 0; j < 4; ++j) {
                    float P = fmaxf(c2a[j] + c2b[j], 0.f);
                    float2 w = w3r[mt * 4 + j];
                    pg = fmaf(P, w.x, pg);
                    pb = fmaf(P, w.y, pb);
                }
            }
            pg += __shfl_xor(pg, 16);
            pb += __shfl_xor(pb, 16);
            pg += __shfl_xor(pg, 32);
            pb += __shfl_xor(pb, 32);
            if (g == q) { ga = pg; be = pb; }
        }

        int m = m0 + tid;
        if (m < M)
            out[(size_t)row * M + m] = fmaf(nrm, ga + b3g, be + b3b);
        // loop-top __syncthreads (staging) guards s_x / chunk-region reuse
    }
}

extern "C" void kernel_launch(void* const* d_in, const int* in_sizes, int n_in,
                              void* d_out, int out_size, void* d_ws, size_t ws_size,
                              hipStream_t stream) {
    const float* x  = (const float*)d_in[0];
    const float* w1 = (const float*)d_in[1];
    const float* b1 = (const float*)d_in[2];
    const float* w2 = (const float*)d_in[3];
    const float* b2 = (const float*)d_in[4];
    const float* w3 = (const float*)d_in[5];
    const float* b3 = (const float*)d_in[6];
    float* out = (float*)d_out;

    const int N = 32768;
    const int M = N - WINDOW + 1;            // 32719
    const int nunits = 32 * 128;             // rows x tiles(256)

    dim3 grid(2048), block(256);
    nsg_kernel<<<grid, block, 0, stream>>>(x, w1, b1, w2, b2, w3, b3,
                                           out, N, M, nunits);
}

// Round 6
// 43.135 us; speedup vs baseline: 1.8835x; 1.8835x over previous
//
#include <hip/hip_runtime.h>
#include <hip/hip_bf16.h>
#include <math.h>

#define WINDOW 50

typedef __attribute__((ext_vector_type(8))) short short8;
typedef __attribute__((ext_vector_type(4))) float f32x4;
typedef unsigned int uint;

union U8 { uint4 u; short8 s; };
__device__ inline short8 as_s8(uint4 u) { U8 t; t.u = u; return t.s; }

// pack (bf16(a) -> low16, bf16(b) -> high16), RNE
__device__ inline uint pk2(float a, float b) {
    uint r;
    asm("v_cvt_pk_bf16_f32 %0, %1, %2" : "=v"(r) : "v"(a), "v"(b));
    return r;
}
__device__ inline float lo_f32(uint u) { return __uint_as_float(u << 16); }
__device__ inline float hi_f32(uint u) { return __uint_as_float(u & 0xffff0000u); }
__device__ inline uint swap16(uint u) { return (u >> 16) | (u << 16); }  // v_alignbit

// Transposed GEMMs (window = MFMA column everywhere). K-space of L2 is
// permuted so L1's C-fragment IS L2's B-fragment after an in-register
// relu + hi/lo split: slot pair (g*8+2j, +1) = (hi,lo) of h1 feature
// nt*16+g*4+j — the exact registers lane (g,w) gets from L1. No LDS
// bounce, no shuffles for the repack. L2 exact: A-words (w2hi,w2lo) and
// swapped (w2lo,w2hi) give (w2hi+w2lo)*(h1hi+h1lo). Stats split-packed in
// L1 K-space (exact), b1 via K16/17 x 1.0. L3 fp32 VALU + shfl_xor reduce.
__global__ __launch_bounds__(256) void nsg_kernel(
    const float* __restrict__ x,
    const float* __restrict__ w1, const float* __restrict__ b1,
    const float* __restrict__ w2, const float* __restrict__ b2,
    const float* __restrict__ w3, const float* __restrict__ b3,
    float* __restrict__ out, int N, int M, int tiles)
{
    __shared__ float s_x[308];            // 306 used
    __shared__ f32x4 s_chunk[296];        // 10-wide chunk moment sums
    __shared__ uint4 s_stat[4][64];       // per-wave split-packed stats

    const int tid = threadIdx.x;
    const int wv  = tid >> 6;
    const int wl  = tid & 63;
    const int l15 = wl & 15;
    const int g   = wl >> 4;
    const int tile = blockIdx.x % tiles;
    const int row  = blockIdx.x / tiles;
    const int m0   = tile * 256;

    // ---- stage x (+halo), clamped ----
    const float* xr = x + (size_t)row * N;
    for (int i = tid; i < 306; i += 256) {
        int gg = m0 + i;
        s_x[i] = (gg < N) ? xr[gg] : 0.0f;
    }

    // ---- constant fragments (overlap staging latency) ----
    // A1: g0 = w1hi pairs (x2), g1 = w1lo pairs (x2), g2 = (b1hi,b1lo) vs 1.0
    short8 A1[4];
    #pragma unroll
    for (int nt = 0; nt < 4; ++nt) {
        int n = nt * 16 + l15;
        float a = w1[n], b = w1[64 + n], c = w1[128 + n], d = w1[192 + n];
        uint hab = pk2(a, b), hcd = pk2(c, d);
        uint lab = pk2(a - lo_f32(hab), b - hi_f32(hab));
        uint lcd = pk2(c - lo_f32(hcd), d - hi_f32(hcd));
        float bb = b1[n];
        uint bh  = pk2(bb, 0.0f);
        uint bpk = pk2(bb, bb - lo_f32(bh));
        uint4 u;
        u.x = (g == 0) ? hab : (g == 1) ? lab : (g == 2) ? bpk : 0u;
        u.y = (g == 0) ? hcd : (g == 1) ? lcd : 0u;
        u.z = (g == 0) ? hab : (g == 1) ? lab : 0u;
        u.w = (g == 0) ? hcd : (g == 1) ? lcd : 0u;
        A1[nt] = as_s8(u);
    }
    // A2: word j of frag (nt,mt) = (w2hi, w2lo) of w2[nt*16+g*4+j][mt*16+l15]
    uint4 A2[4][2];
    #pragma unroll
    for (int nt = 0; nt < 4; ++nt) {
        #pragma unroll
        for (int mt = 0; mt < 2; ++mt) {
            int c = mt * 16 + l15;
            uint w[4];
            #pragma unroll
            for (int j = 0; j < 4; ++j) {
                float a = w2[(nt * 16 + g * 4 + j) * 32 + c];
                uint t = pk2(a, 0.0f);
                w[j] = pk2(a, a - lo_f32(t));
            }
            A2[nt][mt] = make_uint4(w[0], w[1], w[2], w[3]);
        }
    }
    f32x4 b2r[2];
    #pragma unroll
    for (int mt = 0; mt < 2; ++mt)
        b2r[mt] = *(const f32x4*)(b2 + 16 * mt + 4 * g);
    float2 w3r[8];
    #pragma unroll
    for (int mt = 0; mt < 2; ++mt)
        #pragma unroll
        for (int j = 0; j < 4; ++j)
            w3r[mt * 4 + j] = *(const float2*)(w3 + (16 * mt + 4 * g + j) * 2);
    const float b3g = b3[0], b3b = b3[1];
    const uint  K2  = (g == 2) ? 0x3F803F80u : 0u;   // (1.0,1.0) bf16
    const bool  gHi = (g >= 2);

    __syncthreads();   // s_x ready

    // ---- chunk moment-sums (10-wide) ----
    f32x4 myC;
    {
        float S1 = 0.f, S2 = 0.f, S3 = 0.f, S4 = 0.f;
        #pragma unroll
        for (int i = 0; i < 10; ++i) {
            float v = s_x[tid + i], v2 = v * v;
            S1 += v; S2 += v2; S3 = fmaf(v2, v, S3); S4 = fmaf(v2, v2, S4);
        }
        myC = f32x4{S1, S2, S3, S4};
        s_chunk[tid] = myC;
    }
    if (tid < 40) {
        int t = tid + 256;
        float S1 = 0.f, S2 = 0.f, S3 = 0.f, S4 = 0.f;
        #pragma unroll
        for (int i = 0; i < 10; ++i) {
            float v = s_x[t + i], v2 = v * v;
            S1 += v; S2 += v2; S3 = fmaf(v2, v, S3); S4 = fmaf(v2, v2, S4);
        }
        s_chunk[t] = f32x4{S1, S2, S3, S4};
    }
    __syncthreads();   // chunks ready

    // ---- window moments from 5 chunks; split-pack stats ----
    float nrm;
    {
        f32x4 ca = s_chunk[tid + 10], cb = s_chunk[tid + 20];
        f32x4 cc = s_chunk[tid + 30], cd = s_chunk[tid + 40];
        float S1 = myC[0] + ca[0] + cb[0] + cc[0] + cd[0];
        float S2 = myC[1] + ca[1] + cb[1] + cc[1] + cd[1];
        float S3 = myC[2] + ca[2] + cb[2] + cc[2] + cd[2];
        float S4 = myC[3] + ca[3] + cb[3] + cc[3] + cd[3];
        const float invW = 1.0f / (float)WINDOW;
        float mean = S1 * invW;
        float mu2  = mean * mean;
        float c2m = S2 - (float)WINDOW * mu2;
        float c3m = S3 - 3.0f * mean * S2 + 2.0f * (float)WINDOW * mu2 * mean;
        float c4m = S4 - 4.0f * mean * S3 + 6.0f * mu2 * S2
                      - 3.0f * (float)WINDOW * mu2 * mu2;
        float var    = c2m * (1.0f / (float)(WINDOW - 1));
        float sd     = sqrtf(var) + 1e-6f;
        float inv_sd = 1.0f / sd;
        float inv_sd2 = inv_sd * inv_sd;
        float skew = c3m * invW * inv_sd2 * inv_sd;
        float kurt = c4m * invW * inv_sd2 * inv_sd2;
        nrm = (s_x[tid + 25] - mean) * inv_sd;

        uint4 stp;
        uint h01 = pk2(mean, sd), h23 = pk2(skew, kurt);
        stp.x = h01;
        stp.y = h23;
        stp.z = pk2(mean - lo_f32(h01), sd - hi_f32(h01));
        stp.w = pk2(skew - lo_f32(h23), kurt - hi_f32(h23));
        s_stat[wv][wl] = stp;
    }
    // wave-private RAW on s_stat: HW wait + compiler fence (rule-18 pattern)
    asm volatile("s_waitcnt lgkmcnt(0)" ::: "memory");
    __builtin_amdgcn_sched_barrier(0);

    // ---- quarter loop: all-register MLP ----
    float ga = 0.f, be = 0.f;
    #pragma unroll
    for (int q = 0; q < 4; ++q) {
        uint4 st = s_stat[wv][q * 16 + l15];   // 4-way broadcast read
        uint4 bq;
        bq.x = gHi ? K2 : st.x;
        bq.y = gHi ? 0u : st.y;
        bq.z = gHi ? 0u : st.z;
        bq.w = gHi ? 0u : st.w;
        short8 B1 = as_s8(bq);

        f32x4 c2a[2] = { b2r[0], b2r[1] };
        f32x4 c2b[2] = { f32x4{0.f, 0.f, 0.f, 0.f}, f32x4{0.f, 0.f, 0.f, 0.f} };
        #pragma unroll
        for (int nt = 0; nt < 4; ++nt) {
            f32x4 c1 = f32x4{0.f, 0.f, 0.f, 0.f};
            c1 = __builtin_amdgcn_mfma_f32_16x16x32_bf16(A1[nt], B1, c1, 0, 0, 0);
            // relu + hi/lo split, packed directly as L2 B-fragment
            float r0 = fmaxf(c1[0], 0.f), r1 = fmaxf(c1[1], 0.f);
            float r2 = fmaxf(c1[2], 0.f), r3 = fmaxf(c1[3], 0.f);
            uint t01 = pk2(r0, r1), t23 = pk2(r2, r3);
            float l0 = r0 - lo_f32(t01), l1 = r1 - hi_f32(t01);
            float l2 = r2 - lo_f32(t23), l3 = r3 - hi_f32(t23);
            uint4 bb;
            bb.x = pk2(lo_f32(t01), l0);
            bb.y = pk2(hi_f32(t01), l1);
            bb.z = pk2(lo_f32(t23), l2);
            bb.w = pk2(hi_f32(t23), l3);
            short8 B2 = as_s8(bb);
            #pragma unroll
            for (int mt = 0; mt < 2; ++mt) {
                uint4 ah = A2[nt][mt];
                uint4 as2;   // swapped words: (w2lo, w2hi)
                as2.x = swap16(ah.x); as2.y = swap16(ah.y);
                as2.z = swap16(ah.z); as2.w = swap16(ah.w);
                c2a[mt] = __builtin_amdgcn_mfma_f32_16x16x32_bf16(as_s8(ah),  B2, c2a[mt], 0, 0, 0);
                c2b[mt] = __builtin_amdgcn_mfma_f32_16x16x32_bf16(as_s8(as2), B2, c2b[mt], 0, 0, 0);
            }
        }
        // L3 partials (fp32) + 4-group reduce
        float pg = 0.f, pb = 0.f;
        #pragma unroll
        for (int mt = 0; mt < 2; ++mt) {
            #pragma unroll
            for (int j = 0; j < 4; ++j) {
                float P = fmaxf(c2a[mt][j] + c2b[mt][j], 0.f);
                float2 w = w3r[mt * 4 + j];
                pg = fmaf(P, w.x, pg);
                pb = fmaf(P, w.y, pb);
            }
        }
        pg += __shfl_xor(pg, 16);
        pb += __shfl_xor(pb, 16);
        pg += __shfl_xor(pg, 32);
        pb += __shfl_xor(pb, 32);
        if (g == q) { ga = pg; be = pb; }
    }

    // ---- epilogue ----
    int m = m0 + tid;
    if (m < M)
        out[(size_t)row * M + m] = fmaf(nrm, ga + b3g, be + b3b);
}

extern "C" void kernel_launch(void* const* d_in, const int* in_sizes, int n_in,
                              void* d_out, int out_size, void* d_ws, size_t ws_size,
                              hipStream_t stream) {
    const float* x  = (const float*)d_in[0];
    const float* w1 = (const float*)d_in[1];
    const float* b1 = (const float*)d_in[2];
    const float* w2 = (const float*)d_in[3];
    const float* b2 = (const float*)d_in[4];
    const float* w3 = (const float*)d_in[5];
    const float* b3 = (const float*)d_in[6];
    float* out = (float*)d_out;

    const int N = 32768;
    const int B = in_sizes[0] / N;           // 32
    const int M = N - WINDOW + 1;            // 32719
    const int tiles = (M + 255) / 256;       // 128

    dim3 grid(B * tiles), block(256);
    nsg_kernel<<<grid, block, 0, stream>>>(x, w1, b1, w2, b2, w3, b3,
                                           out, N, M, tiles);
}

// Round 7
// 42.751 us; speedup vs baseline: 1.9004x; 1.0090x over previous
//
#include <hip/hip_runtime.h>
#include <hip/hip_bf16.h>
#include <math.h>

#define WINDOW 50

typedef __attribute__((ext_vector_type(8))) short short8;
typedef __attribute__((ext_vector_type(4))) float f32x4;
typedef unsigned int uint;

union U8 { uint4 u; short8 s; };
union UF4 { uint4 u; f32x4 f; };
__device__ inline short8 as_s8(uint4 u) { U8 t; t.u = u; return t.s; }
__device__ inline f32x4  as_f4(uint4 u) { UF4 t; t.u = u; return t.f; }

// pack (bf16(a) -> low16, bf16(b) -> high16), RNE
__device__ inline uint pk2(float a, float b) {
    uint r;
    asm("v_cvt_pk_bf16_f32 %0, %1, %2" : "=v"(r) : "v"(a), "v"(b));
    return r;
}
__device__ inline float lo_f32(uint u) { return __uint_as_float(u << 16); }
__device__ inline float hi_f32(uint u) { return __uint_as_float(u & 0xffff0000u); }

// ---------------- prep: build all weight fragments once into d_ws ----------------
// ws layout (uint4, indexed [frag][lane]):
//   0..3   A1[nt]           (w1^T split: g0=w1hi x2, g1=w1lo x2, g2=(b1hi,b1lo))
//   4..11  A2[nt][mt]       word j = (w2hi, w2lo) of w2[nt*16+g*4+j][mt*16+l15]
//   12..13 b2r[mt]          f32x4 b2[16*mt+4*g ..]
//   14..17 w3 quads         frag 14+mt*2+jj = w3[(16*mt+4*g+2*jj)*2 .. +3]
__global__ __launch_bounds__(64) void nsg_prep(
    const float* __restrict__ w1, const float* __restrict__ b1,
    const float* __restrict__ w2, const float* __restrict__ b2,
    const float* __restrict__ w3, uint4* __restrict__ ws)
{
    const int wl  = threadIdx.x;
    const int l15 = wl & 15;
    const int g   = wl >> 4;

    #pragma unroll
    for (int nt = 0; nt < 4; ++nt) {
        int n = nt * 16 + l15;
        float a = w1[n], b = w1[64 + n], c = w1[128 + n], d = w1[192 + n];
        uint hab = pk2(a, b), hcd = pk2(c, d);
        uint lab = pk2(a - lo_f32(hab), b - hi_f32(hab));
        uint lcd = pk2(c - lo_f32(hcd), d - hi_f32(hcd));
        float bb = b1[n];
        uint bh  = pk2(bb, 0.0f);
        uint bpk = pk2(bb, bb - lo_f32(bh));
        uint4 u;
        u.x = (g == 0) ? hab : (g == 1) ? lab : (g == 2) ? bpk : 0u;
        u.y = (g == 0) ? hcd : (g == 1) ? lcd : 0u;
        u.z = (g == 0) ? hab : (g == 1) ? lab : 0u;
        u.w = (g == 0) ? hcd : (g == 1) ? lcd : 0u;
        ws[nt * 64 + wl] = u;
    }
    #pragma unroll
    for (int nt = 0; nt < 4; ++nt) {
        #pragma unroll
        for (int mt = 0; mt < 2; ++mt) {
            int c = mt * 16 + l15;
            uint w[4];
            #pragma unroll
            for (int j = 0; j < 4; ++j) {
                float a = w2[(nt * 16 + g * 4 + j) * 32 + c];
                uint t = pk2(a, 0.0f);
                w[j] = pk2(a, a - lo_f32(t));
            }
            ws[(4 + nt * 2 + mt) * 64 + wl] = make_uint4(w[0], w[1], w[2], w[3]);
        }
    }
    #pragma unroll
    for (int mt = 0; mt < 2; ++mt)
        ws[(12 + mt) * 64 + wl] = *(const uint4*)(b2 + 16 * mt + 4 * g);
    #pragma unroll
    for (int mt = 0; mt < 2; ++mt)
        #pragma unroll
        for (int jj = 0; jj < 2; ++jj)
            ws[(14 + mt * 2 + jj) * 64 + wl] =
                *(const uint4*)(w3 + (16 * mt + 4 * g + 2 * jj) * 2);
}

// ---------------- main kernel ----------------
__global__ __launch_bounds__(256) void nsg_kernel(
    const float* __restrict__ x, const uint4* __restrict__ ws,
    const float* __restrict__ b3,
    float* __restrict__ out, int N, int M, int tiles)
{
    __shared__ float s_x[308];
    __shared__ f32x4 s_chunk[296];
    __shared__ uint4 s_stat[4][64];

    const int tid = threadIdx.x;
    const int wv  = tid >> 6;
    const int wl  = tid & 63;
    const int l15 = wl & 15;
    const int g   = wl >> 4;
    const int tile = blockIdx.x % tiles;
    const int row  = blockIdx.x / tiles;
    const int m0   = tile * 256;

    // stage x (+halo)
    const float* xr = x + (size_t)row * N;
    for (int i = tid; i < 306; i += 256) {
        int gg = m0 + i;
        s_x[i] = (gg < N) ? xr[gg] : 0.0f;
    }

    // coalesced fragment loads (prep-built); overlap with staging latency
    short8 A1[4];
    uint4  A2[4][2];
    #pragma unroll
    for (int nt = 0; nt < 4; ++nt) A1[nt] = as_s8(ws[nt * 64 + wl]);
    #pragma unroll
    for (int nt = 0; nt < 4; ++nt)
        #pragma unroll
        for (int mt = 0; mt < 2; ++mt)
            A2[nt][mt] = ws[(4 + nt * 2 + mt) * 64 + wl];
    f32x4 b2r[2];
    #pragma unroll
    for (int mt = 0; mt < 2; ++mt) b2r[mt] = as_f4(ws[(12 + mt) * 64 + wl]);
    f32x4 w3q[4];
    #pragma unroll
    for (int p = 0; p < 4; ++p) w3q[p] = as_f4(ws[(14 + p) * 64 + wl]);
    const float b3g = b3[0], b3b = b3[1];
    const uint  K2  = (g == 2) ? 0x3F803F80u : 0u;   // (1.0,1.0) bf16
    const bool  gHi = (g >= 2);

    __syncthreads();   // s_x ready

    // chunk moment-sums (10-wide)
    f32x4 myC;
    {
        float S1 = 0.f, S2 = 0.f, S3 = 0.f, S4 = 0.f;
        #pragma unroll
        for (int i = 0; i < 10; ++i) {
            float v = s_x[tid + i], v2 = v * v;
            S1 += v; S2 += v2; S3 = fmaf(v2, v, S3); S4 = fmaf(v2, v2, S4);
        }
        myC = f32x4{S1, S2, S3, S4};
        s_chunk[tid] = myC;
    }
    if (tid < 40) {
        int t = tid + 256;
        float S1 = 0.f, S2 = 0.f, S3 = 0.f, S4 = 0.f;
        #pragma unroll
        for (int i = 0; i < 10; ++i) {
            float v = s_x[t + i], v2 = v * v;
            S1 += v; S2 += v2; S3 = fmaf(v2, v, S3); S4 = fmaf(v2, v2, S4);
        }
        s_chunk[t] = f32x4{S1, S2, S3, S4};
    }
    __syncthreads();   // chunks ready

    // window moments from 5 chunks; split-pack stats
    float nrm;
    {
        f32x4 ca = s_chunk[tid + 10], cb = s_chunk[tid + 20];
        f32x4 cc = s_chunk[tid + 30], cd = s_chunk[tid + 40];
        float S1 = myC[0] + ca[0] + cb[0] + cc[0] + cd[0];
        float S2 = myC[1] + ca[1] + cb[1] + cc[1] + cd[1];
        float S3 = myC[2] + ca[2] + cb[2] + cc[2] + cd[2];
        float S4 = myC[3] + ca[3] + cb[3] + cc[3] + cd[3];
        const float invW = 1.0f / (float)WINDOW;
        float mean = S1 * invW;
        float mu2  = mean * mean;
        float c2m = S2 - (float)WINDOW * mu2;
        float c3m = S3 - 3.0f * mean * S2 + 2.0f * (float)WINDOW * mu2 * mean;
        float c4m = S4 - 4.0f * mean * S3 + 6.0f * mu2 * S2
                      - 3.0f * (float)WINDOW * mu2 * mu2;
        float var    = c2m * (1.0f / (float)(WINDOW - 1));
        float sd     = sqrtf(var) + 1e-6f;
        float inv_sd = 1.0f / sd;
        float inv_sd2 = inv_sd * inv_sd;
        float skew = c3m * invW * inv_sd2 * inv_sd;
        float kurt = c4m * invW * inv_sd2 * inv_sd2;
        nrm = (s_x[tid + 25] - mean) * inv_sd;

        uint4 stp;
        uint h01 = pk2(mean, sd), h23 = pk2(skew, kurt);
        stp.x = h01;
        stp.y = h23;
        stp.z = pk2(mean - lo_f32(h01), sd - hi_f32(h01));
        stp.w = pk2(skew - lo_f32(h23), kurt - hi_f32(h23));
        s_stat[wv][wl] = stp;
    }
    // wave-private RAW on s_stat (rule-18 pattern)
    asm volatile("s_waitcnt lgkmcnt(0)" ::: "memory");
    __builtin_amdgcn_sched_barrier(0);

    // quarter loop: phased for ILP — 4 indep L1 MFMAs, then splits, then L2
    float ga = 0.f, be = 0.f;
    #pragma unroll
    for (int q = 0; q < 4; ++q) {
        uint4 st = s_stat[wv][q * 16 + l15];   // 4-way broadcast read
        uint4 bq;
        bq.x = gHi ? K2 : st.x;
        bq.y = gHi ? 0u : st.y;
        bq.z = gHi ? 0u : st.z;
        bq.w = gHi ? 0u : st.w;
        short8 B1 = as_s8(bq);

        f32x4 c1[4];
        #pragma unroll
        for (int nt = 0; nt < 4; ++nt) {
            c1[nt] = f32x4{0.f, 0.f, 0.f, 0.f};
            c1[nt] = __builtin_amdgcn_mfma_f32_16x16x32_bf16(A1[nt], B1, c1[nt], 0, 0, 0);
        }

        f32x4 c2a[2] = { b2r[0], b2r[1] };
        f32x4 c2b[2] = { f32x4{0.f, 0.f, 0.f, 0.f}, f32x4{0.f, 0.f, 0.f, 0.f} };
        #pragma unroll
        for (int nt = 0; nt < 4; ++nt) {
            // relu + hi/lo split; B2 = (hi,lo) pairs, B2s = (lo,hi) pairs
            float r0 = fmaxf(c1[nt][0], 0.f), r1 = fmaxf(c1[nt][1], 0.f);
            float r2 = fmaxf(c1[nt][2], 0.f), r3 = fmaxf(c1[nt][3], 0.f);
            uint t01 = pk2(r0, r1), t23 = pk2(r2, r3);
            float h0 = lo_f32(t01), h1v = hi_f32(t01);
            float h2v = lo_f32(t23), h3v = hi_f32(t23);
            float l0 = r0 - h0, l1 = r1 - h1v, l2 = r2 - h2v, l3 = r3 - h3v;
            uint4 bb, bs;
            bb.x = pk2(h0, l0);  bb.y = pk2(h1v, l1);
            bb.z = pk2(h2v, l2); bb.w = pk2(h3v, l3);
            bs.x = pk2(l0, h0);  bs.y = pk2(l1, h1v);
            bs.z = pk2(l2, h2v); bs.w = pk2(l3, h3v);
            short8 B2 = as_s8(bb), B2s = as_s8(bs);
            #pragma unroll
            for (int mt = 0; mt < 2; ++mt) {
                c2a[mt] = __builtin_amdgcn_mfma_f32_16x16x32_bf16(as_s8(A2[nt][mt]), B2,  c2a[mt], 0, 0, 0);
                c2b[mt] = __builtin_amdgcn_mfma_f32_16x16x32_bf16(as_s8(A2[nt][mt]), B2s, c2b[mt], 0, 0, 0);
            }
        }

        // L3 partials (fp32) + 4-group reduce
        float pg = 0.f, pb = 0.f;
        #pragma unroll
        for (int mt = 0; mt < 2; ++mt) {
            #pragma unroll
            for (int j = 0; j < 4; ++j) {
                float P = fmaxf(c2a[mt][j] + c2b[mt][j], 0.f);
                float wx = w3q[mt * 2 + (j >> 1)][(j & 1) * 2 + 0];
                float wy = w3q[mt * 2 + (j >> 1)][(j & 1) * 2 + 1];
                pg = fmaf(P, wx, pg);
                pb = fmaf(P, wy, pb);
            }
        }
        pg += __shfl_xor(pg, 16);
        pb += __shfl_xor(pb, 16);
        pg += __shfl_xor(pg, 32);
        pb += __shfl_xor(pb, 32);
        if (g == q) { ga = pg; be = pb; }
    }

    int m = m0 + tid;
    if (m < M)
        out[(size_t)row * M + m] = fmaf(nrm, ga + b3g, be + b3b);
}

extern "C" void kernel_launch(void* const* d_in, const int* in_sizes, int n_in,
                              void* d_out, int out_size, void* d_ws, size_t ws_size,
                              hipStream_t stream) {
    const float* x  = (const float*)d_in[0];
    const float* w1 = (const float*)d_in[1];
    const float* b1 = (const float*)d_in[2];
    const float* w2 = (const float*)d_in[3];
    const float* b2 = (const float*)d_in[4];
    const float* w3 = (const float*)d_in[5];
    const float* b3 = (const float*)d_in[6];
    float* out = (float*)d_out;
    uint4* ws = (uint4*)d_ws;

    const int N = 32768;
    const int B = in_sizes[0] / N;           // 32
    const int M = N - WINDOW + 1;            // 32719
    const int tiles = (M + 255) / 256;       // 128

    nsg_prep<<<dim3(1), dim3(64), 0, stream>>>(w1, b1, w2, b2, w3, ws);
    nsg_kernel<<<dim3(B * tiles), dim3(256), 0, stream>>>(x, ws, b3, out, N, M, tiles);
}

// Round 8
// 39.463 us; speedup vs baseline: 2.0588x; 1.0833x over previous
//
#include <hip/hip_runtime.h>
#include <hip/hip_bf16.h>
#include <math.h>

#define WINDOW 50

typedef __attribute__((ext_vector_type(8))) short short8;
typedef __attribute__((ext_vector_type(4))) float f32x4;
typedef unsigned int uint;

union U8 { uint4 u; short8 s; };
union UF4 { uint4 u; f32x4 f; };
__device__ inline short8 as_s8(uint4 u) { U8 t; t.u = u; return t.s; }
__device__ inline f32x4  as_f4(uint4 u) { UF4 t; t.u = u; return t.f; }

// pack (bf16(a) -> low16, bf16(b) -> high16), RNE
__device__ inline uint pk2(float a, float b) {
    uint r;
    asm("v_cvt_pk_bf16_f32 %0, %1, %2" : "=v"(r) : "v"(a), "v"(b));
    return r;
}
__device__ inline float lo_f32(uint u) { return __uint_as_float(u << 16); }
__device__ inline float hi_f32(uint u) { return __uint_as_float(u & 0xffff0000u); }

// same-wave LDS RAW fence: HW drain + compiler ordering (rule-18 pattern)
#define LDS_FENCE() do { asm volatile("s_waitcnt lgkmcnt(0)" ::: "memory"); \
                         __builtin_amdgcn_sched_barrier(0); } while (0)

// ---------------- prep: build all weight fragments once into d_ws ----------------
// ws layout (uint4, [frag][lane]):
//   0..3   A1[nt]      (w1^T split: g0=w1hi x2, g1=w1lo x2, g2=(b1hi,b1lo))
//   4..11  A2[nt][mt]  word j = (w2hi, w2lo) of w2[nt*16+g*4+j][mt*16+l15]
//   12..13 b2r[mt]     f32x4 b2[16*mt+4*g ..]
//   14..17 w3 quads    frag 14+mt*2+jj = w3[(16*mt+4*g+2*jj)*2 .. +3]
__global__ __launch_bounds__(64) void nsg_prep(
    const float* __restrict__ w1, const float* __restrict__ b1,
    const float* __restrict__ w2, const float* __restrict__ b2,
    const float* __restrict__ w3, uint4* __restrict__ ws)
{
    const int wl  = threadIdx.x;
    const int l15 = wl & 15;
    const int g   = wl >> 4;

    #pragma unroll
    for (int nt = 0; nt < 4; ++nt) {
        int n = nt * 16 + l15;
        float a = w1[n], b = w1[64 + n], c = w1[128 + n], d = w1[192 + n];
        uint hab = pk2(a, b), hcd = pk2(c, d);
        uint lab = pk2(a - lo_f32(hab), b - hi_f32(hab));
        uint lcd = pk2(c - lo_f32(hcd), d - hi_f32(hcd));
        float bb = b1[n];
        uint bh  = pk2(bb, 0.0f);
        uint bpk = pk2(bb, bb - lo_f32(bh));
        uint4 u;
        u.x = (g == 0) ? hab : (g == 1) ? lab : (g == 2) ? bpk : 0u;
        u.y = (g == 0) ? hcd : (g == 1) ? lcd : 0u;
        u.z = (g == 0) ? hab : (g == 1) ? lab : 0u;
        u.w = (g == 0) ? hcd : (g == 1) ? lcd : 0u;
        ws[nt * 64 + wl] = u;
    }
    #pragma unroll
    for (int nt = 0; nt < 4; ++nt) {
        #pragma unroll
        for (int mt = 0; mt < 2; ++mt) {
            int c = mt * 16 + l15;
            uint w[4];
            #pragma unroll
            for (int j = 0; j < 4; ++j) {
                float a = w2[(nt * 16 + g * 4 + j) * 32 + c];
                uint t = pk2(a, 0.0f);
                w[j] = pk2(a, a - lo_f32(t));
            }
            ws[(4 + nt * 2 + mt) * 64 + wl] = make_uint4(w[0], w[1], w[2], w[3]);
        }
    }
    #pragma unroll
    for (int mt = 0; mt < 2; ++mt)
        ws[(12 + mt) * 64 + wl] = *(const uint4*)(b2 + 16 * mt + 4 * g);
    #pragma unroll
    for (int mt = 0; mt < 2; ++mt)
        #pragma unroll
        for (int jj = 0; jj < 2; ++jj)
            ws[(14 + mt * 2 + jj) * 64 + wl] =
                *(const uint4*)(w3 + (16 * mt + 4 * g + 2 * jj) * 2);
}

// ---------------- main kernel: barrier-free, wave-independent ----------------
// Each wave owns 64 windows end-to-end. All LDS is wave-private; same-wave
// RAW ordered by LDS_FENCE (no __syncthreads). launch_bounds(...,2) raises
// the VGPR budget so weight fragments stay register-resident (r7's 68-VGPR
// demotion re-loaded them from global inside the q-loop).
__global__ __launch_bounds__(256, 2) void nsg_kernel(
    const float* __restrict__ x, const uint4* __restrict__ ws,
    const float* __restrict__ b3,
    float* __restrict__ out, int N, int M, int tiles)
{
    __shared__ float s_xw[4][128];     // per-wave x slice (113 used)
    __shared__ f32x4 s_ck[4][104];     // per-wave 10-wide chunk moment sums
    __shared__ uint4 s_stat[4][64];    // per-wave split-packed stats

    const int tid = threadIdx.x;
    const int wv  = tid >> 6;
    const int wl  = tid & 63;
    const int l15 = wl & 15;
    const int g   = wl >> 4;
    const int tile = blockIdx.x % tiles;
    const int row  = blockIdx.x / tiles;
    const int m0   = tile * 256 + wv * 64;   // this wave's first window

    // ---- stage this wave's x slice (113 values, load 128 clamped) ----
    const float* xr = x + (size_t)row * N;
    {
        int g0 = m0 + wl, g1 = m0 + 64 + wl;
        s_xw[wv][wl]      = (g0 < N) ? xr[g0] : 0.0f;
        s_xw[wv][64 + wl] = (g1 < N) ? xr[g1] : 0.0f;
    }

    // ---- weight fragments (prep-built, coalesced, L2-resident) ----
    short8 A1[4];
    uint4  A2[4][2];
    #pragma unroll
    for (int nt = 0; nt < 4; ++nt) A1[nt] = as_s8(ws[nt * 64 + wl]);
    #pragma unroll
    for (int nt = 0; nt < 4; ++nt)
        #pragma unroll
        for (int mt = 0; mt < 2; ++mt)
            A2[nt][mt] = ws[(4 + nt * 2 + mt) * 64 + wl];
    f32x4 b2r[2];
    #pragma unroll
    for (int mt = 0; mt < 2; ++mt) b2r[mt] = as_f4(ws[(12 + mt) * 64 + wl]);
    f32x4 w3q[4];
    #pragma unroll
    for (int p = 0; p < 4; ++p) w3q[p] = as_f4(ws[(14 + p) * 64 + wl]);
    const float b3g = b3[0], b3b = b3[1];
    const uint  K2  = (g == 2) ? 0x3F803F80u : 0u;   // (1.0,1.0) bf16
    const bool  gHi = (g >= 2);

    LDS_FENCE();   // s_xw visible to whole wave

    // ---- chunk moment-sums (10-wide), wave-private ----
    f32x4 myC;
    {
        float S1 = 0.f, S2 = 0.f, S3 = 0.f, S4 = 0.f;
        #pragma unroll
        for (int i = 0; i < 10; ++i) {
            float v = s_xw[wv][wl + i], v2 = v * v;
            S1 += v; S2 += v2; S3 = fmaf(v2, v, S3); S4 = fmaf(v2, v2, S4);
        }
        myC = f32x4{S1, S2, S3, S4};
        s_ck[wv][wl] = myC;
    }
    if (wl < 40) {
        float S1 = 0.f, S2 = 0.f, S3 = 0.f, S4 = 0.f;
        #pragma unroll
        for (int i = 0; i < 10; ++i) {
            float v = s_xw[wv][64 + wl + i], v2 = v * v;
            S1 += v; S2 += v2; S3 = fmaf(v2, v, S3); S4 = fmaf(v2, v2, S4);
        }
        s_ck[wv][64 + wl] = f32x4{S1, S2, S3, S4};
    }
    LDS_FENCE();   // chunks visible

    // ---- window moments from 5 chunks; split-pack stats ----
    float nrm;
    {
        f32x4 ca = s_ck[wv][wl + 10], cb = s_ck[wv][wl + 20];
        f32x4 cc = s_ck[wv][wl + 30], cd = s_ck[wv][wl + 40];
        float S1 = myC[0] + ca[0] + cb[0] + cc[0] + cd[0];
        float S2 = myC[1] + ca[1] + cb[1] + cc[1] + cd[1];
        float S3 = myC[2] + ca[2] + cb[2] + cc[2] + cd[2];
        float S4 = myC[3] + ca[3] + cb[3] + cc[3] + cd[3];
        const float invW = 1.0f / (float)WINDOW;
        float mean = S1 * invW;
        float mu2  = mean * mean;
        float c2m = S2 - (float)WINDOW * mu2;
        float c3m = S3 - 3.0f * mean * S2 + 2.0f * (float)WINDOW * mu2 * mean;
        float c4m = S4 - 4.0f * mean * S3 + 6.0f * mu2 * S2
                      - 3.0f * (float)WINDOW * mu2 * mu2;
        float var    = c2m * (1.0f / (float)(WINDOW - 1));
        float sd     = sqrtf(var) + 1e-6f;
        float inv_sd = 1.0f / sd;
        float inv_sd2 = inv_sd * inv_sd;
        float skew = c3m * invW * inv_sd2 * inv_sd;
        float kurt = c4m * invW * inv_sd2 * inv_sd2;
        nrm = (s_xw[wv][wl + 25] - mean) * inv_sd;

        uint4 stp;
        uint h01 = pk2(mean, sd), h23 = pk2(skew, kurt);
        stp.x = h01;
        stp.y = h23;
        stp.z = pk2(mean - lo_f32(h01), sd - hi_f32(h01));
        stp.w = pk2(skew - lo_f32(h23), kurt - hi_f32(h23));
        s_stat[wv][wl] = stp;
    }
    LDS_FENCE();   // stats visible

    // ---- quarter loop: phased all-register MLP ----
    float ga = 0.f, be = 0.f;
    #pragma unroll
    for (int q = 0; q < 4; ++q) {
        uint4 st = s_stat[wv][q * 16 + l15];   // 4-way broadcast read
        uint4 bq;
        bq.x = gHi ? K2 : st.x;
        bq.y = gHi ? 0u : st.y;
        bq.z = gHi ? 0u : st.z;
        bq.w = gHi ? 0u : st.w;
        short8 B1 = as_s8(bq);

        f32x4 c1[4];
        #pragma unroll
        for (int nt = 0; nt < 4; ++nt) {
            c1[nt] = f32x4{0.f, 0.f, 0.f, 0.f};
            c1[nt] = __builtin_amdgcn_mfma_f32_16x16x32_bf16(A1[nt], B1, c1[nt], 0, 0, 0);
        }

        f32x4 c2a[2] = { b2r[0], b2r[1] };
        f32x4 c2b[2] = { f32x4{0.f, 0.f, 0.f, 0.f}, f32x4{0.f, 0.f, 0.f, 0.f} };
        #pragma unroll
        for (int nt = 0; nt < 4; ++nt) {
            // relu + hi/lo split; B2 = (hi,lo) pairs, B2s = (lo,hi) pairs
            float r0 = fmaxf(c1[nt][0], 0.f), r1 = fmaxf(c1[nt][1], 0.f);
            float r2 = fmaxf(c1[nt][2], 0.f), r3 = fmaxf(c1[nt][3], 0.f);
            uint t01 = pk2(r0, r1), t23 = pk2(r2, r3);
            float h0 = lo_f32(t01), h1v = hi_f32(t01);
            float h2v = lo_f32(t23), h3v = hi_f32(t23);
            float l0 = r0 - h0, l1 = r1 - h1v, l2 = r2 - h2v, l3 = r3 - h3v;
            uint4 bb, bs;
            bb.x = pk2(h0, l0);  bb.y = pk2(h1v, l1);
            bb.z = pk2(h2v, l2); bb.w = pk2(h3v, l3);
            bs.x = pk2(l0, h0);  bs.y = pk2(l1, h1v);
            bs.z = pk2(l2, h2v); bs.w = pk2(l3, h3v);
            short8 B2 = as_s8(bb), B2s = as_s8(bs);
            #pragma unroll
            for (int mt = 0; mt < 2; ++mt) {
                c2a[mt] = __builtin_amdgcn_mfma_f32_16x16x32_bf16(as_s8(A2[nt][mt]), B2,  c2a[mt], 0, 0, 0);
                c2b[mt] = __builtin_amdgcn_mfma_f32_16x16x32_bf16(as_s8(A2[nt][mt]), B2s, c2b[mt], 0, 0, 0);
            }
        }

        // L3 partials (fp32) + 4-group reduce
        float pg = 0.f, pb = 0.f;
        #pragma unroll
        for (int mt = 0; mt < 2; ++mt) {
            #pragma unroll
            for (int j = 0; j < 4; ++j) {
                float P = fmaxf(c2a[mt][j] + c2b[mt][j], 0.f);
                float wx = w3q[mt * 2 + (j >> 1)][(j & 1) * 2 + 0];
                float wy = w3q[mt * 2 + (j >> 1)][(j & 1) * 2 + 1];
                pg = fmaf(P, wx, pg);
                pb = fmaf(P, wy, pb);
            }
        }
        pg += __shfl_xor(pg, 16);
        pb += __shfl_xor(pb, 16);
        pg += __shfl_xor(pg, 32);
        pb += __shfl_xor(pb, 32);
        if (g == q) { ga = pg; be = pb; }
    }

    // ---- epilogue ----
    int m = m0 + wl;
    if (m < M)
        out[(size_t)row * M + m] = fmaf(nrm, ga + b3g, be + b3b);
}

extern "C" void kernel_launch(void* const* d_in, const int* in_sizes, int n_in,
                              void* d_out, int out_size, void* d_ws, size_t ws_size,
                              hipStream_t stream) {
    const float* x  = (const float*)d_in[0];
    const float* w1 = (const float*)d_in[1];
    const float* b1 = (const float*)d_in[2];
    const float* w2 = (const float*)d_in[3];
    const float* b2 = (const float*)d_in[4];
    const float* w3 = (const float*)d_in[5];
    const float* b3 = (const float*)d_in[6];
    float* out = (float*)d_out;
    uint4* ws = (uint4*)d_ws;

    const int N = 32768;
    const int B = in_sizes[0] / N;           // 32
    const int M = N - WINDOW + 1;            // 32719
    const int tiles = (M + 255) / 256;       // 128

    nsg_prep<<<dim3(1), dim3(64), 0, stream>>>(w1, b1, w2, b2, w3, ws);
    nsg_kernel<<<dim3(B * tiles), dim3(256), 0, stream>>>(x, ws, b3, out, N, M, tiles);
}